// Round 1
// baseline (31811.102 us; speedup 1.0000x reference)
//
#include <hip/hip_runtime.h>

typedef __attribute__((ext_vector_type(8))) __bf16 bf16x8;
typedef __attribute__((ext_vector_type(4))) float f32x4;

#define NSEQ 32
#define TTOT 2048
#define DIM  512
#define HID  512
#define G4   2048   // 4*H

__device__ __forceinline__ float sigmoidf_(float x) {
    return 1.0f / (1.0f + __expf(-x));
}
__device__ __forceinline__ float tanhf_(float x) {
    return 2.0f / (1.0f + __expf(-2.0f * x)) - 1.0f;
}

// ---------------- init: transpose+convert weights to bf16, seed h/c ----------------
__global__ void lstm_init(const float* __restrict__ Wx, const float* __restrict__ Wh,
                          const float* __restrict__ h0,
                          __bf16* __restrict__ WxbT, __bf16* __restrict__ WhbT,
                          __bf16* __restrict__ hbuf, float* __restrict__ cstate)
{
    int idx = blockIdx.x * 256 + threadIdx.x;   // 0 .. 2048*512-1
    int c = idx & (G4 - 1);                     // column in [0,2048)
    int k = idx >> 11;                          // row    in [0,512)
    WxbT[(size_t)c * DIM + k] = (__bf16)Wx[idx];   // WxbT[c][k] = Wx[k][c]
    WhbT[(size_t)c * HID + k] = (__bf16)Wh[idx];
    if (idx < NSEQ * HID) {
        hbuf[idx]   = (__bf16)h0[idx];          // parity-0 buffer = h_0
        cstate[idx] = 0.0f;
    }
}

// ---------------- stage 1: A = x @ Wx + b for a chunk of Tc timesteps ----------------
// LDS-free bf16 MFMA GEMM. Tile 128x128 per block, 4 waves each 64x64 (4x4 frags).
__global__ __launch_bounds__(256) void gemm_xwx(
    const float* __restrict__ x,      // [32][2048][512] f32
    const __bf16* __restrict__ WxbT,  // [2048][512] bf16 (transposed)
    const float* __restrict__ b,      // [2048]
    float* __restrict__ Axw,          // [32][Tc][2048] f32
    int t0, int ltc)
{
    const int Tc   = 1 << ltc;
    const int cb   = blockIdx.x * 128;   // column base (of 2048)
    const int m0   = blockIdx.y * 128;   // row base (of 32*Tc)
    const int tid  = threadIdx.x;
    const int w    = tid >> 6;
    const int lane = tid & 63;
    const int l15  = lane & 15;
    const int lq   = lane >> 4;           // 0..3
    const int wm   = w >> 1, wn = w & 1;  // 2x2 wave grid

    f32x4 acc[4][4] = {};

    const float* xrow[4];
#pragma unroll
    for (int mi = 0; mi < 4; ++mi) {
        int r  = m0 + wm * 64 + mi * 16 + l15;
        int n  = r >> ltc;
        int tl = r & (Tc - 1);
        xrow[mi] = x + ((size_t)n * TTOT + (t0 + tl)) * DIM;
    }
    const __bf16* bcol[4];
#pragma unroll
    for (int ni = 0; ni < 4; ++ni)
        bcol[ni] = WxbT + (size_t)(cb + wn * 64 + ni * 16 + l15) * DIM;

    for (int k0 = 0; k0 < DIM; k0 += 32) {
        bf16x8 af[4], bfr[4];
#pragma unroll
        for (int mi = 0; mi < 4; ++mi) {
            const float* p = xrow[mi] + k0 + lq * 8;
            f32x4 f0 = *(const f32x4*)p;
            f32x4 f1 = *(const f32x4*)(p + 4);
            bf16x8 a;
            a[0] = (__bf16)f0[0]; a[1] = (__bf16)f0[1]; a[2] = (__bf16)f0[2]; a[3] = (__bf16)f0[3];
            a[4] = (__bf16)f1[0]; a[5] = (__bf16)f1[1]; a[6] = (__bf16)f1[2]; a[7] = (__bf16)f1[3];
            af[mi] = a;
        }
#pragma unroll
        for (int ni = 0; ni < 4; ++ni)
            bfr[ni] = *(const bf16x8*)(bcol[ni] + k0 + lq * 8);
#pragma unroll
        for (int mi = 0; mi < 4; ++mi)
#pragma unroll
            for (int ni = 0; ni < 4; ++ni)
                acc[mi][ni] = __builtin_amdgcn_mfma_f32_16x16x32_bf16(af[mi], bfr[ni], acc[mi][ni], 0, 0, 0);
    }

    // epilogue: C/D layout col=lane&15, row=(lane>>4)*4+j  [verified m89]
#pragma unroll
    for (int ni = 0; ni < 4; ++ni) {
        int col = cb + wn * 64 + ni * 16 + l15;
        float bias = b[col];
#pragma unroll
        for (int mi = 0; mi < 4; ++mi) {
#pragma unroll
            for (int j = 0; j < 4; ++j) {
                int r  = m0 + wm * 64 + mi * 16 + lq * 4 + j;
                int n  = r >> ltc;
                int tl = r & (Tc - 1);
                Axw[((size_t)n * Tc + tl) * G4 + col] = acc[mi][ni][j] + bias;
            }
        }
    }
}

// ---------------- stage 2: persistent sliced recurrence ----------------
// 32 WGs (1/CU), WG g owns h-cols [g*16, g*16+16) => gate cols {j, 512+j, 1024+j, 1536+j}.
// Wave w (0..3) owns gate block w (i/f/o/g), 16 cols, Wh slice held in registers as
// bf16 MFMA B-fragments (16 K-tiles x 4 VGPR). One counter-barrier per step.
__global__ __launch_bounds__(256, 1) void lstm_rec(
    const float* __restrict__ Axw,    // [32][Tc][2048]
    const __bf16* __restrict__ WhbT,  // [2048][512]
    __bf16* __restrict__ hbuf,        // [2][32][512] bf16
    float* __restrict__ cstate,       // [32][512]
    unsigned int* __restrict__ counters, // [2048]
    float* __restrict__ out,          // [32][2048][512]
    int t0, int Tc)
{
    const int g    = blockIdx.x;      // 0..31
    const int tid  = threadIdx.x;
    const int w    = tid >> 6;        // gate block
    const int lane = tid & 63;
    const int l15  = lane & 15;
    const int lq   = lane >> 4;

    // persistent B-fragments: B[k][n], n = l15 (gate col), k = kt*32 + lq*8 + e
    bf16x8 bfrag[16];
    {
        const __bf16* base = WhbT + (size_t)(w * HID + g * 16 + l15) * HID + lq * 8;
#pragma unroll
        for (int kt = 0; kt < 16; ++kt)
            bfrag[kt] = *(const bf16x8*)(base + kt * 32);
    }

    // gates-phase thread mapping: (s2, jloc) handles seqs {s2, s2+16} at h-col g*16+jloc
    const int jloc = tid & 15;
    const int s2   = tid >> 4;        // 0..15
    const int hcol = g * 16 + jloc;
    float c_a = cstate[s2 * HID + hcol];
    float c_b = cstate[(s2 + 16) * HID + hcol];

    __shared__ float S_lds[32][65];   // padded: conflict-free

    for (int t = t0; t < t0 + Tc; ++t) {
        if (t > 0) {
            // relaxed spin (agent-scope atomic load bypasses L1), then acquire fence
            while (__hip_atomic_load(&counters[t - 1], __ATOMIC_RELAXED,
                                     __HIP_MEMORY_SCOPE_AGENT) < 32u) {}
            __threadfence();
        }

        // S = h_t @ Wh_slice  (A frags read straight from bf16 h buffer)
        const __bf16* hb = hbuf + (size_t)(t & 1) * (NSEQ * HID);
        f32x4 acc0 = {0, 0, 0, 0}, acc1 = {0, 0, 0, 0};
#pragma unroll
        for (int kt = 0; kt < 16; ++kt) {
            bf16x8 a0 = *(const bf16x8*)(hb + (size_t)l15 * HID + kt * 32 + lq * 8);
            bf16x8 a1 = *(const bf16x8*)(hb + (size_t)(l15 + 16) * HID + kt * 32 + lq * 8);
            acc0 = __builtin_amdgcn_mfma_f32_16x16x32_bf16(a0, bfrag[kt], acc0, 0, 0, 0);
            acc1 = __builtin_amdgcn_mfma_f32_16x16x32_bf16(a1, bfrag[kt], acc1, 0, 0, 0);
        }

        // cross-wave exchange of gate pre-activations
#pragma unroll
        for (int j = 0; j < 4; ++j) {
            S_lds[lq * 4 + j][w * 16 + l15]      = acc0[j];
            S_lds[16 + lq * 4 + j][w * 16 + l15] = acc1[j];
        }
        __syncthreads();

        // gates + cell update (fp32)
        {
            int tloc = t - t0;
            const float* Ap0 = Axw + ((size_t)s2 * Tc + tloc) * G4;
            const float* Ap1 = Axw + ((size_t)(s2 + 16) * Tc + tloc) * G4;

            float ai0 = S_lds[s2][jloc]      + Ap0[hcol];
            float af0 = S_lds[s2][16 + jloc] + Ap0[HID + hcol];
            float ao0 = S_lds[s2][32 + jloc] + Ap0[2 * HID + hcol];
            float ag0 = S_lds[s2][48 + jloc] + Ap0[3 * HID + hcol];
            float ii = sigmoidf_(ai0), ff = sigmoidf_(af0);
            float oo = sigmoidf_(ao0), gg = tanhf_(ag0);
            c_a = ff * c_a + ii * gg;
            float hA = oo * tanhf_(c_a);

            float ai1 = S_lds[s2 + 16][jloc]      + Ap1[hcol];
            float af1 = S_lds[s2 + 16][16 + jloc] + Ap1[HID + hcol];
            float ao1 = S_lds[s2 + 16][32 + jloc] + Ap1[2 * HID + hcol];
            float ag1 = S_lds[s2 + 16][48 + jloc] + Ap1[3 * HID + hcol];
            float ii1 = sigmoidf_(ai1), ff1 = sigmoidf_(af1);
            float oo1 = sigmoidf_(ao1), gg1 = tanhf_(ag1);
            c_b = ff1 * c_b + ii1 * gg1;
            float hB = oo1 * tanhf_(c_b);

            out[((size_t)s2 * TTOT + t) * HID + hcol]        = hA;
            out[((size_t)(s2 + 16) * TTOT + t) * HID + hcol] = hB;

            __bf16* hn = hbuf + (size_t)((t + 1) & 1) * (NSEQ * HID);
            hn[s2 * HID + hcol]        = (__bf16)hA;
            hn[(s2 + 16) * HID + hcol] = (__bf16)hB;
        }

        __threadfence();   // commit h writes to coherence point (agent scope)
        __syncthreads();   // all waves of this WG done before signaling
        if (tid == 0)
            __hip_atomic_fetch_add(&counters[t], 1u, __ATOMIC_RELEASE,
                                   __HIP_MEMORY_SCOPE_AGENT);
    }

    // persist cell state for next chunk launch
    cstate[s2 * HID + hcol]        = c_a;
    cstate[(s2 + 16) * HID + hcol] = c_b;
}

extern "C" void kernel_launch(void* const* d_in, const int* in_sizes, int n_in,
                              void* d_out, int out_size, void* d_ws, size_t ws_size,
                              hipStream_t stream)
{
    const float* x  = (const float*)d_in[0];
    const float* h0 = (const float*)d_in[1];
    const float* Wx = (const float*)d_in[2];
    const float* Wh = (const float*)d_in[3];
    const float* b  = (const float*)d_in[4];
    float* out = (float*)d_out;

    char* ws = (char*)d_ws;
    __bf16* WxbT = (__bf16*)(ws);                                  // 2 MB
    __bf16* WhbT = (__bf16*)(ws + (2u << 20));                     // 2 MB
    __bf16* hbuf = (__bf16*)(ws + (4u << 20));                     // 64 KB
    float* cstate = (float*)(ws + (4u << 20) + (64u << 10));       // 64 KB
    unsigned int* counters = (unsigned int*)(ws + (4u << 20) + (128u << 10)); // 8 KB
    float* Axw = (float*)(ws + (4u << 20) + (256u << 10));
    const size_t base = (4u << 20) + (256u << 10);

    // pick largest chunk Tc in {256,...,16} whose A-buffer fits in ws
    int ltc = 8;
    while (ltc > 4 && base + (((size_t)NSEQ << ltc) * G4 * sizeof(float)) > ws_size) --ltc;
    const int Tc = 1 << ltc;

    hipMemsetAsync(counters, 0, TTOT * sizeof(unsigned int), stream);
    lstm_init<<<dim3((G4 * DIM) / 256), dim3(256), 0, stream>>>(Wx, Wh, h0, WxbT, WhbT, hbuf, cstate);

    for (int t0 = 0; t0 < TTOT; t0 += Tc) {
        gemm_xwx<<<dim3(G4 / 128, (NSEQ * Tc) / 128), dim3(256), 0, stream>>>(
            x, WxbT, b, Axw, t0, ltc);
        lstm_rec<<<dim3(32), dim3(256), 0, stream>>>(
            Axw, WhbT, hbuf, cstate, counters, out, t0, Tc);
    }
}

// Round 2
// 8275.440 us; speedup vs baseline: 3.8440x; 3.8440x over previous
//
#include <hip/hip_runtime.h>

typedef __attribute__((ext_vector_type(8))) __bf16 bf16x8;
typedef __attribute__((ext_vector_type(4))) float f32x4;
typedef unsigned int u32;
typedef unsigned long long u64;

#define NSEQ 32
#define TTOT 2048
#define DIM  512
#define HID  512
#define G4   2048   // 4*H

__device__ __forceinline__ float sigmoidf_(float x) {
    return 1.0f / (1.0f + __expf(-x));
}
__device__ __forceinline__ float tanhf_(float x) {
    return 2.0f / (1.0f + __expf(-2.0f * x)) - 1.0f;
}

// ---------------- init: transpose+convert weights, seed tagged h0, scrub ring ----------------
__global__ void lstm_init(const float* __restrict__ Wx, const float* __restrict__ Wh,
                          const float* __restrict__ h0,
                          __bf16* __restrict__ WxbT, __bf16* __restrict__ WhbT,
                          u32* __restrict__ hctag, float* __restrict__ cstate,
                          int* __restrict__ progress)
{
    int idx = blockIdx.x * 256 + threadIdx.x;   // 0 .. 2048*512-1
    int c = idx & (G4 - 1);
    int k = idx >> 11;
    WxbT[(size_t)c * DIM + k] = (__bf16)Wx[idx];
    WhbT[(size_t)c * HID + k] = (__bf16)Wh[idx];
    if (idx < 4 * NSEQ * HID) {                 // scrub all 4 ring slots (stale-tag safety across replays)
        u32 v = 0;
        if (idx < NSEQ * HID) {                 // slot 0 = h_0, tag 1
            __bf16 hb = (__bf16)h0[idx];
            v = ((u32)__builtin_bit_cast(unsigned short, hb) << 16) | 1u;
        }
        hctag[idx] = v;
    }
    if (idx < NSEQ * HID) cstate[idx] = 0.0f;
    if (idx < 32) progress[idx] = -1;
}

// ---------------- stage 1: A = x @ Wx + b for a chunk of Tc timesteps ----------------
__global__ __launch_bounds__(256) void gemm_xwx(
    const float* __restrict__ x,      // [32][2048][512] f32
    const __bf16* __restrict__ WxbT,  // [2048][512] bf16 (transposed)
    const float* __restrict__ b,      // [2048]
    float* __restrict__ Axw,          // [32][Tc][2048] f32
    int t0, int ltc)
{
    const int Tc   = 1 << ltc;
    const int cb   = blockIdx.x * 128;
    const int m0   = blockIdx.y * 128;
    const int tid  = threadIdx.x;
    const int w    = tid >> 6;
    const int lane = tid & 63;
    const int l15  = lane & 15;
    const int lq   = lane >> 4;
    const int wm   = w >> 1, wn = w & 1;

    f32x4 acc[4][4] = {};

    const float* xrow[4];
#pragma unroll
    for (int mi = 0; mi < 4; ++mi) {
        int r  = m0 + wm * 64 + mi * 16 + l15;
        int n  = r >> ltc;
        int tl = r & (Tc - 1);
        xrow[mi] = x + ((size_t)n * TTOT + (t0 + tl)) * DIM;
    }
    const __bf16* bcol[4];
#pragma unroll
    for (int ni = 0; ni < 4; ++ni)
        bcol[ni] = WxbT + (size_t)(cb + wn * 64 + ni * 16 + l15) * DIM;

    for (int k0 = 0; k0 < DIM; k0 += 32) {
        bf16x8 af[4], bfr[4];
#pragma unroll
        for (int mi = 0; mi < 4; ++mi) {
            const float* p = xrow[mi] + k0 + lq * 8;
            f32x4 f0 = *(const f32x4*)p;
            f32x4 f1 = *(const f32x4*)(p + 4);
            bf16x8 a;
            a[0] = (__bf16)f0[0]; a[1] = (__bf16)f0[1]; a[2] = (__bf16)f0[2]; a[3] = (__bf16)f0[3];
            a[4] = (__bf16)f1[0]; a[5] = (__bf16)f1[1]; a[6] = (__bf16)f1[2]; a[7] = (__bf16)f1[3];
            af[mi] = a;
        }
#pragma unroll
        for (int ni = 0; ni < 4; ++ni)
            bfr[ni] = *(const bf16x8*)(bcol[ni] + k0 + lq * 8);
#pragma unroll
        for (int mi = 0; mi < 4; ++mi)
#pragma unroll
            for (int ni = 0; ni < 4; ++ni)
                acc[mi][ni] = __builtin_amdgcn_mfma_f32_16x16x32_bf16(af[mi], bfr[ni], acc[mi][ni], 0, 0, 0);
    }

#pragma unroll
    for (int ni = 0; ni < 4; ++ni) {
        int col = cb + wn * 64 + ni * 16 + l15;
        float bias = b[col];
#pragma unroll
        for (int mi = 0; mi < 4; ++mi) {
#pragma unroll
            for (int j = 0; j < 4; ++j) {
                int r  = m0 + wm * 64 + mi * 16 + lq * 4 + j;
                int n  = r >> ltc;
                int tl = r & (Tc - 1);
                Axw[((size_t)n * Tc + tl) * G4 + col] = acc[mi][ni][j] + bias;
            }
        }
    }
}

// ---------------- stage 2: persistent sliced recurrence, fence-free ----------------
// 32 WGs; WG g owns h-cols [g*16, g*16+16). h exchange via tagged u32 atomics at the
// coherence point (IF): value = bf16<<16 | (step_tag). Ring of 4 slots; progress[] for
// overwrite flow-control (2 steps of slack, off critical path).
__global__ __launch_bounds__(256, 1) void lstm_rec(
    const float* __restrict__ Axw,    // [32][Tc][2048]
    const __bf16* __restrict__ WhbT,  // [2048][512]
    u32* __restrict__ hctag,          // [4][32][512] tagged
    float* __restrict__ cstate,       // [32][512]
    int* __restrict__ progress,       // [32]
    float* __restrict__ out,          // [32][2048][512]
    int t0, int Tc)
{
    const int g    = blockIdx.x;
    const int tid  = threadIdx.x;
    const int w    = tid >> 6;
    const int lane = tid & 63;
    const int l15  = lane & 15;
    const int lq   = lane >> 4;

    // persistent Wh B-fragments (16 K-tiles x 4 VGPR)
    bf16x8 bfrag[16];
    {
        const __bf16* base = WhbT + (size_t)(w * HID + g * 16 + l15) * HID + lq * 8;
#pragma unroll
        for (int kt = 0; kt < 16; ++kt)
            bfrag[kt] = *(const bf16x8*)(base + kt * 32);
    }

    const int jloc = tid & 15;
    const int s2   = tid >> 4;
    const int hcol = g * 16 + jloc;
    float c_a = cstate[s2 * HID + hcol];
    float c_b = cstate[(s2 + 16) * HID + hcol];

    __shared__ __align__(16) unsigned char hs[32 * 1024];  // staged h, XOR-swizzled [32][512] bf16
    __shared__ float S_lds[32][65];

    for (int t = t0; t < t0 + Tc; ++t) {
        // flow-control probe (wave 0 only); latency hides under the h-poll below
        int pl = 0x7fffffff;
        if (w == 0)
            pl = __hip_atomic_load(&progress[lane & 31], __ATOMIC_RELAXED, __HIP_MEMORY_SCOPE_AGENT);

        // prefetch this step's input contributions (L2-cached, latency hidden)
        const int tloc = t - t0;
        const float* Ap0 = Axw + ((size_t)s2 * Tc + tloc) * G4;
        const float* Ap1 = Axw + ((size_t)(s2 + 16) * Tc + tloc) * G4;
        float ax0 = Ap0[hcol],           ax1 = Ap0[HID + hcol];
        float ax2 = Ap0[2 * HID + hcol], ax3 = Ap0[3 * HID + hcol];
        float ax4 = Ap1[hcol],           ax5 = Ap1[HID + hcol];
        float ax6 = Ap1[2 * HID + hcol], ax7 = Ap1[3 * HID + hcol];

        // tag-validated cache-bypass read of h_t (one IF round-trip in steady state)
        const u32 expect = (u32)((t + 1) & 0xffff);
        const u64 pat = (u64)expect | ((u64)expect << 32);
        const u64* hp = (const u64*)(hctag + (size_t)(t & 3) * (NSEQ * HID));
        u64 hv[32];
        bool ok;
        do {
            ok = true;
#pragma unroll
            for (int i = 0; i < 32; ++i)
                hv[i] = __hip_atomic_load(&hp[i * 256 + tid], __ATOMIC_RELAXED, __HIP_MEMORY_SCOPE_AGENT);
#pragma unroll
            for (int i = 0; i < 32; ++i)
                ok = ok && ((hv[i] & 0x0000ffff0000ffffull) == pat);
        } while (!ok);

        // finish flow-control check for writing h_{t+1} over h_{t-3}
        if (w == 0) {
            const int need = t - 3;
            while (!__all(pl >= need))
                pl = __hip_atomic_load(&progress[lane & 31], __ATOMIC_RELAXED, __HIP_MEMORY_SCOPE_AGENT);
        }

        // stage stripped bf16 into swizzled LDS: thread tid writes row i, cols {2*tid, 2*tid+1}
#pragma unroll
        for (int i = 0; i < 32; ++i) {
            u32 lo = (u32)hv[i], hi = (u32)(hv[i] >> 32);
            u32 packed = (lo >> 16) | (hi & 0xffff0000u);
            *(u32*)(hs + ((i * 1024 + 4 * tid) ^ ((i & 7) << 4))) = packed;
        }
        __syncthreads();

        // publish consumption of h_t (frees slot t&3 for h_{t+4})
        if (tid == 0)
            __hip_atomic_exchange(&progress[g], t, __ATOMIC_RELAXED, __HIP_MEMORY_SCOPE_AGENT);

        // S = h_t @ Wh_slice from LDS (swizzled b128 reads, ~2-way conflicts = free)
        f32x4 acc0 = {0, 0, 0, 0}, acc1 = {0, 0, 0, 0};
        const int xr = (l15 & 7) << 4;
#pragma unroll
        for (int kt = 0; kt < 16; ++kt) {
            bf16x8 a0 = *(const bf16x8*)(hs + ((l15 * 1024 + kt * 64 + lq * 16) ^ xr));
            bf16x8 a1 = *(const bf16x8*)(hs + (((l15 + 16) * 1024 + kt * 64 + lq * 16) ^ xr));
            acc0 = __builtin_amdgcn_mfma_f32_16x16x32_bf16(a0, bfrag[kt], acc0, 0, 0, 0);
            acc1 = __builtin_amdgcn_mfma_f32_16x16x32_bf16(a1, bfrag[kt], acc1, 0, 0, 0);
        }

        // cross-wave exchange of gate pre-activations
#pragma unroll
        for (int j = 0; j < 4; ++j) {
            S_lds[lq * 4 + j][w * 16 + l15]      = acc0[j];
            S_lds[16 + lq * 4 + j][w * 16 + l15] = acc1[j];
        }
        __syncthreads();

        // gates + cell update (fp32)
        float hA, hB;
        {
            float ai0 = S_lds[s2][jloc]      + ax0;
            float af0 = S_lds[s2][16 + jloc] + ax1;
            float ao0 = S_lds[s2][32 + jloc] + ax2;
            float ag0 = S_lds[s2][48 + jloc] + ax3;
            float ii = sigmoidf_(ai0), ff = sigmoidf_(af0);
            float oo = sigmoidf_(ao0), gg = tanhf_(ag0);
            c_a = ff * c_a + ii * gg;
            hA = oo * tanhf_(c_a);

            float ai1 = S_lds[s2 + 16][jloc]      + ax4;
            float af1 = S_lds[s2 + 16][16 + jloc] + ax5;
            float ao1 = S_lds[s2 + 16][32 + jloc] + ax6;
            float ag1 = S_lds[s2 + 16][48 + jloc] + ax7;
            float ii1 = sigmoidf_(ai1), ff1 = sigmoidf_(af1);
            float oo1 = sigmoidf_(ao1), gg1 = tanhf_(ag1);
            c_b = ff1 * c_b + ii1 * gg1;
            hB = oo1 * tanhf_(c_b);
        }

        out[((size_t)s2 * TTOT + t) * HID + hcol]        = hA;
        out[((size_t)(s2 + 16) * TTOT + t) * HID + hcol] = hB;

        // publish tagged h_{t+1} at the coherence point (RMW => cross-XCD visible, no fence)
        {
            u32 tg2 = (u32)((t + 2) & 0xffff);
            u32 vA = ((u32)__builtin_bit_cast(unsigned short, (__bf16)hA) << 16) | tg2;
            u32 vB = ((u32)__builtin_bit_cast(unsigned short, (__bf16)hB) << 16) | tg2;
            u32* dst = hctag + (size_t)((t + 1) & 3) * (NSEQ * HID);
            __hip_atomic_exchange(&dst[s2 * HID + hcol], vA, __ATOMIC_RELAXED, __HIP_MEMORY_SCOPE_AGENT);
            __hip_atomic_exchange(&dst[(s2 + 16) * HID + hcol], vB, __ATOMIC_RELAXED, __HIP_MEMORY_SCOPE_AGENT);
        }
    }

    cstate[s2 * HID + hcol]        = c_a;
    cstate[(s2 + 16) * HID + hcol] = c_b;
}

extern "C" void kernel_launch(void* const* d_in, const int* in_sizes, int n_in,
                              void* d_out, int out_size, void* d_ws, size_t ws_size,
                              hipStream_t stream)
{
    const float* x  = (const float*)d_in[0];
    const float* h0 = (const float*)d_in[1];
    const float* Wx = (const float*)d_in[2];
    const float* Wh = (const float*)d_in[3];
    const float* b  = (const float*)d_in[4];
    float* out = (float*)d_out;

    char* ws = (char*)d_ws;
    __bf16* WxbT   = (__bf16*)(ws);                                // 2 MB
    __bf16* WhbT   = (__bf16*)(ws + (2u << 20));                   // 2 MB
    u32*    hctag  = (u32*)(ws + (4u << 20));                      // 256 KB (4 slots)
    float*  cstate = (float*)(ws + (4u << 20) + (256u << 10));     // 64 KB
    int*    progress = (int*)(ws + (4u << 20) + (320u << 10));     // 128 B
    float*  Axw    = (float*)(ws + (4u << 20) + (384u << 10));
    const size_t base = (4u << 20) + (384u << 10);

    // largest chunk Tc in {2048,...,16} whose A-buffer fits in ws
    int ltc = 11;
    while (ltc > 4 && base + (((size_t)NSEQ << ltc) * G4 * sizeof(float)) > ws_size) --ltc;
    const int Tc = 1 << ltc;

    lstm_init<<<dim3((G4 * DIM) / 256), dim3(256), 0, stream>>>(
        Wx, Wh, h0, WxbT, WhbT, hctag, cstate, progress);

    for (int t0 = 0; t0 < TTOT; t0 += Tc) {
        gemm_xwx<<<dim3(G4 / 128, (NSEQ << ltc) / 128), dim3(256), 0, stream>>>(
            x, WxbT, b, Axw, t0, ltc);
        lstm_rec<<<dim3(32), dim3(256), 0, stream>>>(
            Axw, WhbT, hctag, cstate, progress, out, t0, Tc);
    }
}